// Round 16
// baseline (155.035 us; speedup 1.0000x reference)
//
#include <hip/hip_runtime.h>
#include <hip/hip_bf16.h>
#include <cstdint>

#define B_  16
#define TP  4096
#define TQ  512
#define D2_ 256
#define TI 128
#define TJ 32
#define NJT (TQ / TJ)   // 16
#define NFRAG 35        // 16 S-frags + 2 ext + 16 PV + 1 qm
#define NBX (TP / TI)   // 32

typedef _Float16 f16x8 __attribute__((ext_vector_type(8)));
typedef _Float16 f16x4 __attribute__((ext_vector_type(4)));
typedef float    f32x4 __attribute__((ext_vector_type(4)));
typedef uint32_t u32;

// ---- fragment blob stash: slice-3 (last 1KB) of G rows 0..8959 ----
// phat partials: slice-3 floats [768..1024) of G rows 9000..9511.
// k_main writes only slices 0..2 of G rows; k_g3 (last) overwrites slice 3.
__device__ __forceinline__ _Float16* frag_ptr(float* G, int b, int jt, int f, int lane) {
  return (_Float16*)G + ((size_t)((b * NJT + jt) * NFRAG + f)) * 2048 + 1536 + lane * 8;
}
__device__ __forceinline__ float* phat_ptr(float* G, int b, int blk) {
  return G + (size_t)(9000 + b * NBX + blk) * 1024 + 768;
}

// async global->LDS, 16B per lane; lds base must be wave-uniform
__device__ __forceinline__ void gload_lds16(const _Float16* g, _Float16* l) {
  __builtin_amdgcn_global_load_lds(
      (const __attribute__((address_space(1))) void*)g,
      (__attribute__((address_space(3))) void*)l, 16, 0, 0);
}

// K-slot permutation for PV operands: pi(g*8+e) = g*4+e (e<4) else 16+g*4+e-4.
__device__ __forceinline__ int kperm(int g, int e) {
  return (e < 4) ? (g * 4 + e) : (16 + g * 4 + (e - 4));
}

// ---------------- kernel 0: build f16 fragments (S-A, ext, PV-B, qm) ----------------
__global__ __launch_bounds__(256) void k_prep(const float* __restrict__ U,
                                              const float* __restrict__ w,
                                              const int* __restrict__ mq,
                                              float* __restrict__ G) {
  __shared__ _Float16 T[TJ][264];
  __shared__ float uds[TJ];
  __shared__ float qs[TJ];
  const int b = blockIdx.y, jt = blockIdx.x;
  const int tid = threadIdx.x, lane = tid & 63, wv = tid >> 6;
  const int l15 = lane & 15, g = lane >> 4;

  if (tid < TJ) qs[tid] = (float)mq[b * TQ + jt * TJ + tid];

#pragma unroll
  for (int it = 0; it < 8; ++it) {
    int chunk = it * 256 + tid;
    int r = chunk >> 6, c = (chunk & 63) * 4;
    int row = b * TQ + jt * TJ + r;
    float qmv = (float)mq[row];
    f32x4 u = *(const f32x4*)&U[(size_t)row * D2_ + c];
    f16x4 v;
    v[0] = (_Float16)(u.x * qmv); v[1] = (_Float16)(u.y * qmv);
    v[2] = (_Float16)(u.z * qmv); v[3] = (_Float16)(u.w * qmv);
    *(f16x4*)&T[r][c] = v;
  }
  __syncthreads();

  {
    int r = tid >> 3, s = tid & 7;
    float p = 0.f;
#pragma unroll
    for (int e = 0; e < 32; ++e) p += (float)T[r][s * 32 + e] * w[D2_ + s * 32 + e];
    p += __shfl_xor(p, 1); p += __shfl_xor(p, 2); p += __shfl_xor(p, 4);
    if (s == 0) uds[r] = p;
  }
  __syncthreads();

#pragma unroll
  for (int q = 0; q < 9; ++q) {
    int f = q * 4 + wv;
    if (f >= NFRAG) continue;
    f16x8 v;
#pragma unroll
    for (int e = 0; e < 8; ++e) v[e] = (_Float16)0.0f;
    if (f < 16) {
      int t = f >> 3, ks = f & 7;
      v = *(const f16x8*)&T[t * 16 + l15][ks * 32 + g * 8];
    } else if (f < 18) {
      int t = f - 16;
      if (g == 0) { v[0] = (_Float16)uds[t * 16 + l15]; v[1] = (_Float16)1.0f; }
    } else if (f < 34) {
      int n = f - 18;
#pragma unroll
      for (int e = 0; e < 8; ++e) v[e] = T[kperm(g, e)][n * 16 + l15];
    } else {
#pragma unroll
      for (int e = 0; e < 8; ++e) v[e] = (_Float16)qs[kperm(g, e)];
    }
    *(f16x8*)frag_ptr(G, b, jt, f, lane) = v;
  }
}

// ---------------- kernel 1: R15 + s_setprio around MFMA clusters ----------------
__global__ __launch_bounds__(1024, 4) void k_main(
    const float* __restrict__ H, const float* __restrict__ w,
    const int* __restrict__ mp,
    float* __restrict__ mblk_g, float* __restrict__ lblk_g,
    float* __restrict__ G) {

  __shared__ char smem[72704];
  _Float16 (*Fbuf)[NFRAG][512] = (_Float16(*)[NFRAG][512])smem;   // 2 x 35840 B
  float* mtmp = (float*)(smem + 71680);                            // 128 f32
  float* wrow = mtmp + 128;                                        // 128 f32
  _Float16 (*Uatt)[264] = (_Float16(*)[264])smem;                  // epilogue overlay (67584 B)
  f32x4 (*Part)[64]     = (f32x4(*)[64])smem;                      // late overlay (16384 B)

  // XCD clustering: hw id i -> XCD i%8 hosts batches {2x, 2x+1} only.
  const int i = blockIdx.x;
  const int x = i & 7, m = i >> 3;
  const int b  = 2 * x + (m >> 5);
  const int bx = m & 31;
  const int i0 = bx * TI;

  const int tid = threadIdx.x, lane = tid & 63, wv = tid >> 6;   // wv 0..15
  const int l15 = lane & 15, g = lane >> 4;
  const int pr = wv >> 1;        // 0..7: rows i0 + pr*16 .. +15
  const int h  = wv & 1;         // c-half for PV

  const _Float16* Gf = (const _Float16*)G;
  auto tilebase = [&](int jt) {
    return Gf + ((size_t)((b * NJT + jt) * NFRAG)) * 2048 + 1536 + (size_t)lane * 8;
  };

  // ---- issue tile-0 async stages into Fbuf[0]: 16 waves cover 35 frags ----
  {
    const _Float16* fb = tilebase(0);
#pragma unroll
    for (int q = 0; q < 3; ++q) {
      int f = q * 16 + wv;
      if (f < NFRAG) gload_lds16(fb + (size_t)f * 2048, &Fbuf[0][f][0]);
    }
  }

  // ---- prologue: h-frags (B-operand: col=l15=i, k=c) + hdot ----
  const int rowg = i0 + pr * 16 + l15;
  const float* Hrow = H + ((size_t)b * TP + rowg) * D2_;
  const float pmr = (float)mp[b * TP + rowg];
  f16x8 afr[8];
  float hp = 0.f;
#pragma unroll
  for (int ks = 0; ks < 8; ++ks) {
    int c0 = ks * 32 + g * 8;
    f32x4 h0 = *(const f32x4*)&Hrow[c0];
    f32x4 h1 = *(const f32x4*)&Hrow[c0 + 4];
    f32x4 wh0 = *(const f32x4*)&w[c0];
    f32x4 wh1 = *(const f32x4*)&w[c0 + 4];
    f32x4 wu0 = *(const f32x4*)&w[2 * D2_ + c0];
    f32x4 wu1 = *(const f32x4*)&w[2 * D2_ + c0 + 4];
    h0 *= pmr; h1 *= pmr;
    f16x8 a;
    a[0] = (_Float16)(h0.x * wu0.x); a[1] = (_Float16)(h0.y * wu0.y);
    a[2] = (_Float16)(h0.z * wu0.z); a[3] = (_Float16)(h0.w * wu0.w);
    a[4] = (_Float16)(h1.x * wu1.x); a[5] = (_Float16)(h1.y * wu1.y);
    a[6] = (_Float16)(h1.z * wu1.z); a[7] = (_Float16)(h1.w * wu1.w);
    afr[ks] = a;
    hp += h0.x * wh0.x + h0.y * wh0.y + h0.z * wh0.z + h0.w * wh0.w
        + h1.x * wh1.x + h1.y * wh1.y + h1.z * wh1.z + h1.w * wh1.w;
  }
  hp += __shfl_xor(hp, 16);
  hp += __shfl_xor(hp, 32);              // hdot for i = l15 of this pr
  f16x8 bext;
#pragma unroll
  for (int e = 0; e < 8; ++e) bext[e] = (_Float16)0.0f;
  if (g == 0) { bext[0] = (_Float16)1.0f; bext[1] = (_Float16)hp; }

  __syncthreads();   // drains tile-0 stages

  f32x4 Oacc[8];
#pragma unroll
  for (int n = 0; n < 8; ++n) Oacc[n] = {0.f, 0.f, 0.f, 0.f};
  f32x4 Lacc = {0.f, 0.f, 0.f, 0.f};
  float m_run  = -1e30f;
  float m_true = -1e30f;

  int cur = 0;
  for (int jt = 0; jt < NJT; ++jt) {
    // ---- issue next-tile async stages into the other buffer ----
    if (jt + 1 < NJT) {
      const _Float16* fb = tilebase(jt + 1);
#pragma unroll
      for (int q = 0; q < 3; ++q) {
        int f = q * 16 + wv;
        if (f < NFRAG) gload_lds16(fb + (size_t)f * 2048, &Fbuf[cur ^ 1][f][0]);
      }
    }

    // ---- S^T: mfma(A=Um-frag, B=h-frag) -> C[j = g*4+reg (+16)][i = l15] ----
    f32x4 S0 = {0.f, 0.f, 0.f, 0.f}, S1 = {0.f, 0.f, 0.f, 0.f};
    __builtin_amdgcn_s_setprio(1);
#pragma unroll
    for (int ks = 0; ks < 8; ++ks) {
      f16x8 a0 = *(const f16x8*)&Fbuf[cur][ks][lane * 8];
      f16x8 a1 = *(const f16x8*)&Fbuf[cur][8 + ks][lane * 8];
      S0 = __builtin_amdgcn_mfma_f32_16x16x32_f16(a0, afr[ks], S0, 0, 0, 0);
      S1 = __builtin_amdgcn_mfma_f32_16x16x32_f16(a1, afr[ks], S1, 0, 0, 0);
    }
    {
      f16x8 ax0 = *(const f16x8*)&Fbuf[cur][16][lane * 8];
      f16x8 ax1 = *(const f16x8*)&Fbuf[cur][17][lane * 8];
      S0 = __builtin_amdgcn_mfma_f32_16x16x32_f16(ax0, bext, S0, 0, 0, 0);
      S1 = __builtin_amdgcn_mfma_f32_16x16x32_f16(ax1, bext, S1, 0, 0, 0);
    }
    __builtin_amdgcn_s_setprio(0);

    // ---- softmax (lane-local in i=l15), deferred rescale ----
    float lmax = fmaxf(fmaxf(fmaxf(S0[0], S0[1]), fmaxf(S0[2], S0[3])),
                       fmaxf(fmaxf(S1[0], S1[1]), fmaxf(S1[2], S1[3])));
    lmax = fmaxf(lmax, __shfl_xor(lmax, 16));
    lmax = fmaxf(lmax, __shfl_xor(lmax, 32));   // row max over all 32 j
    m_true = fmaxf(m_true, lmax);
    if (__any(lmax - m_run > 8.0f)) {
      float mn = fmaxf(m_run, lmax);
      float sc = __expf(m_run - mn);
      m_run = mn;
#pragma unroll
      for (int reg = 0; reg < 4; ++reg) {
        float scr = __shfl(sc, g * 4 + reg);
        Lacc[reg] *= scr;
#pragma unroll
        for (int n = 0; n < 8; ++n) Oacc[n][reg] *= scr;
      }
    }

    // ---- P in-register: lane (l15,g) holds exactly k-slots pi(g*8+e) ----
    union { u32 u[4]; f16x8 v; } paw;
    paw.u[0] = __builtin_bit_cast(u32, __builtin_amdgcn_cvt_pkrtz(
                   __expf(S0[0] - m_run), __expf(S0[1] - m_run)));
    paw.u[1] = __builtin_bit_cast(u32, __builtin_amdgcn_cvt_pkrtz(
                   __expf(S0[2] - m_run), __expf(S0[3] - m_run)));
    paw.u[2] = __builtin_bit_cast(u32, __builtin_amdgcn_cvt_pkrtz(
                   __expf(S1[0] - m_run), __expf(S1[1] - m_run)));
    paw.u[3] = __builtin_bit_cast(u32, __builtin_amdgcn_cvt_pkrtz(
                   __expf(S1[2] - m_run), __expf(S1[3] - m_run)));
    f16x8 pa = paw.v;

    // ---- PV (K=32, permuted) + l via qm-frag ----
    __builtin_amdgcn_s_setprio(1);
    {
      f16x8 qmf = *(const f16x8*)&Fbuf[cur][34][lane * 8];
      Lacc = __builtin_amdgcn_mfma_f32_16x16x32_f16(pa, qmf, Lacc, 0, 0, 0);
    }
#pragma unroll
    for (int n = 0; n < 8; ++n) {
      f16x8 bu = *(const f16x8*)&Fbuf[cur][18 + h * 8 + n][lane * 8];
      Oacc[n] = __builtin_amdgcn_mfma_f32_16x16x32_f16(pa, bu, Oacc[n], 0, 0, 0);
    }
    __builtin_amdgcn_s_setprio(0);

    __syncthreads();   // all waves done with Fbuf[cur]; next-tile stages drained
    cur ^= 1;
  }

  // ---- block-level b-softmax partials setup ----
  if (h == 0 && lane < 16) mtmp[pr * 16 + lane] = m_true;   // true row max, 128 rows
  float inv_l[4];
#pragma unroll
  for (int reg = 0; reg < 4; ++reg) inv_l[reg] = 1.0f / Lacc[reg];
  __syncthreads();   // mtmp visible; Fbuf dead -> overlays OK

  if (wv == 0) {     // wave 0: m_blk, wrow, l_blk over 128 rows
    float v0 = mtmp[lane], v1 = mtmp[lane + 64];
    float v = fmaxf(v0, v1);
#pragma unroll
    for (int o = 1; o < 64; o <<= 1) v = fmaxf(v, __shfl_xor(v, o));
    float m_blk = v;
    float pm0 = (float)mp[b * TP + i0 + lane];
    float pm1 = (float)mp[b * TP + i0 + lane + 64];
    float wr0 = pm0 * __expf(v0 - m_blk);
    float wr1 = pm1 * __expf(v1 - m_blk);
    wrow[lane] = wr0;
    wrow[lane + 64] = wr1;
    float ls = wr0 + wr1;
#pragma unroll
    for (int o = 1; o < 64; o <<= 1) ls += __shfl_xor(ls, o);
    if (lane == 0) { mblk_g[b * NBX + bx] = m_blk; lblk_g[b * NBX + bx] = ls; }
  }

  // park U_att (f16) in overlay
#pragma unroll
  for (int n = 0; n < 8; ++n)
#pragma unroll
    for (int reg = 0; reg < 4; ++reg)
      Uatt[pr * 16 + g * 4 + reg][h * 128 + n * 16 + l15] =
          (_Float16)(Oacc[n][reg] * inv_l[reg]);
  __syncthreads();   // Uatt + wrow ready

  // ---- G writes (NT stores; cached loads) + weighted-Hm accumulation ----
  const int* pmb = mp + b * TP + i0;
  f32x4 acc = {0.f, 0.f, 0.f, 0.f};
#pragma unroll
  for (int it = 0; it < 8; ++it) {
    int idx4 = it * 1024 + tid;
    int r = idx4 >> 6, c = (idx4 & 63) * 4;
    float pm = (float)pmb[r];
    f32x4 hv = *(const f32x4*)&H[((size_t)b * TP + i0 + r) * D2_ + c];
    hv *= pm;                                   // Hm
    f16x4 u4 = *(const f16x4*)&Uatt[r][c];
    f32x4 u; u.x = (float)u4[0]; u.y = (float)u4[1]; u.z = (float)u4[2]; u.w = (float)u4[3];
    size_t ro = ((size_t)b * TP + i0 + r) * (4 * D2_);
    __builtin_nontemporal_store(hv, (f32x4*)&G[ro + c]);
    f32x4 up = u * pm;
    __builtin_nontemporal_store(up, (f32x4*)&G[ro + D2_ + c]);
    f32x4 hu; hu.x = hv.x * u.x; hu.y = hv.y * u.y; hu.z = hv.z * u.z; hu.w = hv.w * u.w;
    __builtin_nontemporal_store(hu, (f32x4*)&G[ro + 2 * D2_ + c]);
    acc += wrow[r] * hv;                        // h_att partial
  }

  __syncthreads();                // done reading Uatt
  Part[wv][lane] = acc;           // overlay
  __syncthreads();
  if (tid < 64) {
    f32x4 s = Part[0][tid];
#pragma unroll
    for (int k = 1; k < 16; ++k) s += Part[k][tid];
    *(f32x4*)&phat_ptr(G, b, bx)[tid * 4] = s;
  }
}

// ---------------- kernel 2: combine h_att partials ----------------
__global__ __launch_bounds__(256) void k_comb(const float* __restrict__ Gc,
    const float* __restrict__ mblk_g, const float* __restrict__ lblk_g,
    float* __restrict__ hatt) {
  int b = blockIdx.x, tid = threadIdx.x;
  __shared__ float sm[NBX], sl[NBX];
  if (tid < NBX) { sm[tid] = mblk_g[b * NBX + tid]; sl[tid] = lblk_g[b * NBX + tid]; }
  __syncthreads();
  float M = -1e30f;
#pragma unroll
  for (int k = 0; k < NBX; ++k) M = fmaxf(M, sm[k]);
  float L = 0.f;
#pragma unroll
  for (int k = 0; k < NBX; ++k) L += __expf(sm[k] - M) * sl[k];
  float acc = 0.f;
  for (int k = 0; k < NBX; ++k)
    acc += __expf(sm[k] - M) * Gc[(size_t)(9000 + b * NBX + k) * 1024 + 768 + tid];
  hatt[b * D2_ + tid] = acc / L;
}

// ---------------- kernel 3: G slice 3 = Hm * h_att (NT load dead H, NT store) ----------------
__global__ __launch_bounds__(1024) void k_g3(const float* __restrict__ H,
    const int* __restrict__ mp, const float* __restrict__ hatt,
    float* __restrict__ G) {
  const int total = B_ * TP * (D2_ / 4);
  for (int idx = blockIdx.x * 1024 + threadIdx.x; idx < total; idx += gridDim.x * 1024) {
    int c4 = idx & 63;
    int i = (idx >> 6) & (TP - 1);
    int b = idx >> 18;
    float pm = (float)mp[b * TP + i];
    f32x4 h = __builtin_nontemporal_load((const f32x4*)&H[((size_t)b * TP + i) * D2_ + c4 * 4]);
    f32x4 ha = *(const f32x4*)&hatt[b * D2_ + c4 * 4];
    f32x4 o;
    o.x = h.x * pm * ha.x; o.y = h.y * pm * ha.y;
    o.z = h.z * pm * ha.z; o.w = h.w * pm * ha.w;
    __builtin_nontemporal_store(o, (f32x4*)&G[((size_t)b * TP + i) * (4 * D2_) + 3 * D2_ + c4 * 4]);
  }
}

extern "C" void kernel_launch(void* const* d_in, const int* in_sizes, int n_in,
                              void* d_out, int out_size, void* d_ws, size_t ws_size,
                              hipStream_t stream) {
  const float* H  = (const float*)d_in[0];
  const float* U  = (const float*)d_in[1];
  const float* w  = (const float*)d_in[2];
  const int*   mp = (const int*)d_in[3];
  const int*   mq = (const int*)d_in[4];
  float* G = (float*)d_out;

  float* ws   = (float*)d_ws;
  float* mblk = ws;             // 512
  float* lblk = mblk + 1024;    // 512
  float* hatt = lblk + 1024;    // 4096

  k_prep<<<dim3(NJT, B_), 256, 0, stream>>>(U, w, mq, G);
  k_main<<<dim3(NBX * B_), 1024, 0, stream>>>(H, w, mp, mblk, lblk, G);
  k_comb<<<dim3(B_), 256, 0, stream>>>(G, mblk, lblk, hatt);
  k_g3<<<dim3(512), 1024, 0, stream>>>(H, mp, hatt, G);
}

// Round 17
// 149.990 us; speedup vs baseline: 1.0336x; 1.0336x over previous
//
#include <hip/hip_runtime.h>
#include <hip/hip_bf16.h>
#include <cstdint>

#define B_  16
#define TP  4096
#define TQ  512
#define D2_ 256
#define TI 128
#define TJ 32
#define NJT (TQ / TJ)   // 16
#define NFRAG 35        // 16 S-frags + 2 ext + 16 PV + 1 qm
#define NBX (TP / TI)   // 32

typedef _Float16 f16x8 __attribute__((ext_vector_type(8)));
typedef _Float16 f16x4 __attribute__((ext_vector_type(4)));
typedef float    f32x4 __attribute__((ext_vector_type(4)));
typedef uint32_t u32;

// ---- fragment blob stash: slice-3 (last 1KB) of G rows 0..8959 ----
// phat partials: slice-3 floats [768..1024) of G rows 9000..9511.
// k_main writes only slices 0..2 of G rows; k_g3 (last) overwrites slice 3.
__device__ __forceinline__ _Float16* frag_ptr(float* G, int b, int jt, int f, int lane) {
  return (_Float16*)G + ((size_t)((b * NJT + jt) * NFRAG + f)) * 2048 + 1536 + lane * 8;
}
__device__ __forceinline__ float* phat_ptr(float* G, int b, int blk) {
  return G + (size_t)(9000 + b * NBX + blk) * 1024 + 768;
}

// async global->LDS, 16B per lane; lds base must be wave-uniform
__device__ __forceinline__ void gload_lds16(const _Float16* g, _Float16* l) {
  __builtin_amdgcn_global_load_lds(
      (const __attribute__((address_space(1))) void*)g,
      (__attribute__((address_space(3))) void*)l, 16, 0, 0);
}

// K-slot permutation for PV operands: pi(g*8+e) = g*4+e (e<4) else 16+g*4+e-4.
__device__ __forceinline__ int kperm(int g, int e) {
  return (e < 4) ? (g * 4 + e) : (16 + g * 4 + (e - 4));
}

// ---------------- kernel 0: build f16 fragments (S-A, ext, PV-B, qm) ----------------
__global__ __launch_bounds__(256) void k_prep(const float* __restrict__ U,
                                              const float* __restrict__ w,
                                              const int* __restrict__ mq,
                                              float* __restrict__ G) {
  __shared__ _Float16 T[TJ][264];
  __shared__ float uds[TJ];
  __shared__ float qs[TJ];
  const int b = blockIdx.y, jt = blockIdx.x;
  const int tid = threadIdx.x, lane = tid & 63, wv = tid >> 6;
  const int l15 = lane & 15, g = lane >> 4;

  if (tid < TJ) qs[tid] = (float)mq[b * TQ + jt * TJ + tid];

#pragma unroll
  for (int it = 0; it < 8; ++it) {
    int chunk = it * 256 + tid;
    int r = chunk >> 6, c = (chunk & 63) * 4;
    int row = b * TQ + jt * TJ + r;
    float qmv = (float)mq[row];
    f32x4 u = *(const f32x4*)&U[(size_t)row * D2_ + c];
    f16x4 v;
    v[0] = (_Float16)(u.x * qmv); v[1] = (_Float16)(u.y * qmv);
    v[2] = (_Float16)(u.z * qmv); v[3] = (_Float16)(u.w * qmv);
    *(f16x4*)&T[r][c] = v;
  }
  __syncthreads();

  {
    int r = tid >> 3, s = tid & 7;
    float p = 0.f;
#pragma unroll
    for (int e = 0; e < 32; ++e) p += (float)T[r][s * 32 + e] * w[D2_ + s * 32 + e];
    p += __shfl_xor(p, 1); p += __shfl_xor(p, 2); p += __shfl_xor(p, 4);
    if (s == 0) uds[r] = p;
  }
  __syncthreads();

#pragma unroll
  for (int q = 0; q < 9; ++q) {
    int f = q * 4 + wv;
    if (f >= NFRAG) continue;
    f16x8 v;
#pragma unroll
    for (int e = 0; e < 8; ++e) v[e] = (_Float16)0.0f;
    if (f < 16) {
      int t = f >> 3, ks = f & 7;
      v = *(const f16x8*)&T[t * 16 + l15][ks * 32 + g * 8];
    } else if (f < 18) {
      int t = f - 16;
      if (g == 0) { v[0] = (_Float16)uds[t * 16 + l15]; v[1] = (_Float16)1.0f; }
    } else if (f < 34) {
      int n = f - 18;
#pragma unroll
      for (int e = 0; e < 8; ++e) v[e] = T[kperm(g, e)][n * 16 + l15];
    } else {
#pragma unroll
      for (int e = 0; e < 8; ++e) v[e] = (_Float16)qs[kperm(g, e)];
    }
    *(f16x8*)frag_ptr(G, b, jt, f, lane) = v;
  }
}

// ---------------- kernel 1: R11 structure + XCD clustering + NT G-stores only ----------------
__global__ __launch_bounds__(1024, 4) void k_main(
    const float* __restrict__ H, const float* __restrict__ w,
    const int* __restrict__ mp,
    float* __restrict__ mblk_g, float* __restrict__ lblk_g,
    float* __restrict__ G) {

  __shared__ char smem[72704];
  _Float16 (*Fbuf)[NFRAG][512] = (_Float16(*)[NFRAG][512])smem;   // 2 x 35840 B
  float* mtmp = (float*)(smem + 71680);                            // 128 f32
  float* wrow = mtmp + 128;                                        // 128 f32
  _Float16 (*Uatt)[264] = (_Float16(*)[264])smem;                  // epilogue overlay (67584 B)
  f32x4 (*Part)[64]     = (f32x4(*)[64])smem;                      // late overlay (16384 B)

  // XCD clustering: hw id i -> XCD i%8 hosts batches {2x, 2x+1} only.
  const int i = blockIdx.x;
  const int x = i & 7, m = i >> 3;
  const int b  = 2 * x + (m >> 5);
  const int bx = m & 31;
  const int i0 = bx * TI;

  const int tid = threadIdx.x, lane = tid & 63, wv = tid >> 6;   // wv 0..15
  const int l15 = lane & 15, g = lane >> 4;
  const int pr = wv >> 1;        // 0..7: rows i0 + pr*16 .. +15
  const int h  = wv & 1;         // c-half for PV

  const _Float16* Gf = (const _Float16*)G;
  auto tilebase = [&](int jt) {
    return Gf + ((size_t)((b * NJT + jt) * NFRAG)) * 2048 + 1536 + (size_t)lane * 8;
  };

  // ---- issue tile-0 async stages into Fbuf[0]: 16 waves cover 35 frags ----
  {
    const _Float16* fb = tilebase(0);
#pragma unroll
    for (int q = 0; q < 3; ++q) {
      int f = q * 16 + wv;
      if (f < NFRAG) gload_lds16(fb + (size_t)f * 2048, &Fbuf[0][f][0]);
    }
  }

  // ---- prologue: h-frags (B-operand: col=l15=i, k=c) + hdot ----
  const int rowg = i0 + pr * 16 + l15;
  const float* Hrow = H + ((size_t)b * TP + rowg) * D2_;
  const float pmr = (float)mp[b * TP + rowg];
  f16x8 afr[8];
  float hp = 0.f;
#pragma unroll
  for (int ks = 0; ks < 8; ++ks) {
    int c0 = ks * 32 + g * 8;
    f32x4 h0 = *(const f32x4*)&Hrow[c0];
    f32x4 h1 = *(const f32x4*)&Hrow[c0 + 4];
    f32x4 wh0 = *(const f32x4*)&w[c0];
    f32x4 wh1 = *(const f32x4*)&w[c0 + 4];
    f32x4 wu0 = *(const f32x4*)&w[2 * D2_ + c0];
    f32x4 wu1 = *(const f32x4*)&w[2 * D2_ + c0 + 4];
    h0 *= pmr; h1 *= pmr;
    f16x8 a;
    a[0] = (_Float16)(h0.x * wu0.x); a[1] = (_Float16)(h0.y * wu0.y);
    a[2] = (_Float16)(h0.z * wu0.z); a[3] = (_Float16)(h0.w * wu0.w);
    a[4] = (_Float16)(h1.x * wu1.x); a[5] = (_Float16)(h1.y * wu1.y);
    a[6] = (_Float16)(h1.z * wu1.z); a[7] = (_Float16)(h1.w * wu1.w);
    afr[ks] = a;
    hp += h0.x * wh0.x + h0.y * wh0.y + h0.z * wh0.z + h0.w * wh0.w
        + h1.x * wh1.x + h1.y * wh1.y + h1.z * wh1.z + h1.w * wh1.w;
  }
  hp += __shfl_xor(hp, 16);
  hp += __shfl_xor(hp, 32);              // hdot for i = l15 of this pr
  f16x8 bext;
#pragma unroll
  for (int e = 0; e < 8; ++e) bext[e] = (_Float16)0.0f;
  if (g == 0) { bext[0] = (_Float16)1.0f; bext[1] = (_Float16)hp; }

  __syncthreads();   // drains tile-0 stages

  f32x4 Oacc[8];
#pragma unroll
  for (int n = 0; n < 8; ++n) Oacc[n] = {0.f, 0.f, 0.f, 0.f};
  f32x4 Lacc = {0.f, 0.f, 0.f, 0.f};
  float m_run  = -1e30f;
  float m_true = -1e30f;

  int cur = 0;
  for (int jt = 0; jt < NJT; ++jt) {
    // ---- issue next-tile async stages into the other buffer ----
    if (jt + 1 < NJT) {
      const _Float16* fb = tilebase(jt + 1);
#pragma unroll
      for (int q = 0; q < 3; ++q) {
        int f = q * 16 + wv;
        if (f < NFRAG) gload_lds16(fb + (size_t)f * 2048, &Fbuf[cur ^ 1][f][0]);
      }
    }

    // ---- S^T: mfma(A=Um-frag, B=h-frag) -> C[j = g*4+reg (+16)][i = l15] ----
    f32x4 S0 = {0.f, 0.f, 0.f, 0.f}, S1 = {0.f, 0.f, 0.f, 0.f};
#pragma unroll
    for (int ks = 0; ks < 8; ++ks) {
      f16x8 a0 = *(const f16x8*)&Fbuf[cur][ks][lane * 8];
      f16x8 a1 = *(const f16x8*)&Fbuf[cur][8 + ks][lane * 8];
      S0 = __builtin_amdgcn_mfma_f32_16x16x32_f16(a0, afr[ks], S0, 0, 0, 0);
      S1 = __builtin_amdgcn_mfma_f32_16x16x32_f16(a1, afr[ks], S1, 0, 0, 0);
    }
    {
      f16x8 ax0 = *(const f16x8*)&Fbuf[cur][16][lane * 8];
      f16x8 ax1 = *(const f16x8*)&Fbuf[cur][17][lane * 8];
      S0 = __builtin_amdgcn_mfma_f32_16x16x32_f16(ax0, bext, S0, 0, 0, 0);
      S1 = __builtin_amdgcn_mfma_f32_16x16x32_f16(ax1, bext, S1, 0, 0, 0);
    }

    // ---- softmax (lane-local in i=l15), deferred rescale ----
    float lmax = fmaxf(fmaxf(fmaxf(S0[0], S0[1]), fmaxf(S0[2], S0[3])),
                       fmaxf(fmaxf(S1[0], S1[1]), fmaxf(S1[2], S1[3])));
    lmax = fmaxf(lmax, __shfl_xor(lmax, 16));
    lmax = fmaxf(lmax, __shfl_xor(lmax, 32));   // row max over all 32 j
    m_true = fmaxf(m_true, lmax);
    if (__any(lmax - m_run > 8.0f)) {
      float mn = fmaxf(m_run, lmax);
      float sc = __expf(m_run - mn);
      m_run = mn;
#pragma unroll
      for (int reg = 0; reg < 4; ++reg) {
        float scr = __shfl(sc, g * 4 + reg);
        Lacc[reg] *= scr;
#pragma unroll
        for (int n = 0; n < 8; ++n) Oacc[n][reg] *= scr;
      }
    }

    // ---- P in-register: lane (l15,g) holds exactly k-slots pi(g*8+e) ----
    union { u32 u[4]; f16x8 v; } paw;
    paw.u[0] = __builtin_bit_cast(u32, __builtin_amdgcn_cvt_pkrtz(
                   __expf(S0[0] - m_run), __expf(S0[1] - m_run)));
    paw.u[1] = __builtin_bit_cast(u32, __builtin_amdgcn_cvt_pkrtz(
                   __expf(S0[2] - m_run), __expf(S0[3] - m_run)));
    paw.u[2] = __builtin_bit_cast(u32, __builtin_amdgcn_cvt_pkrtz(
                   __expf(S1[0] - m_run), __expf(S1[1] - m_run)));
    paw.u[3] = __builtin_bit_cast(u32, __builtin_amdgcn_cvt_pkrtz(
                   __expf(S1[2] - m_run), __expf(S1[3] - m_run)));
    f16x8 pa = paw.v;

    // ---- PV (K=32, permuted) + l via qm-frag ----
    {
      f16x8 qmf = *(const f16x8*)&Fbuf[cur][34][lane * 8];
      Lacc = __builtin_amdgcn_mfma_f32_16x16x32_f16(pa, qmf, Lacc, 0, 0, 0);
    }
#pragma unroll
    for (int n = 0; n < 8; ++n) {
      f16x8 bu = *(const f16x8*)&Fbuf[cur][18 + h * 8 + n][lane * 8];
      Oacc[n] = __builtin_amdgcn_mfma_f32_16x16x32_f16(pa, bu, Oacc[n], 0, 0, 0);
    }

    __syncthreads();   // all waves done with Fbuf[cur]; next-tile stages drained
    cur ^= 1;
  }

  // ---- block-level b-softmax partials setup ----
  if (h == 0 && lane < 16) mtmp[pr * 16 + lane] = m_true;   // true row max, 128 rows
  float inv_l[4];
#pragma unroll
  for (int reg = 0; reg < 4; ++reg) inv_l[reg] = 1.0f / Lacc[reg];
  __syncthreads();   // mtmp visible; Fbuf dead -> overlays OK

  if (wv == 0) {     // wave 0: m_blk, wrow, l_blk over 128 rows
    float v0 = mtmp[lane], v1 = mtmp[lane + 64];
    float v = fmaxf(v0, v1);
#pragma unroll
    for (int o = 1; o < 64; o <<= 1) v = fmaxf(v, __shfl_xor(v, o));
    float m_blk = v;
    float pm0 = (float)mp[b * TP + i0 + lane];
    float pm1 = (float)mp[b * TP + i0 + lane + 64];
    float wr0 = pm0 * __expf(v0 - m_blk);
    float wr1 = pm1 * __expf(v1 - m_blk);
    wrow[lane] = wr0;
    wrow[lane + 64] = wr1;
    float ls = wr0 + wr1;
#pragma unroll
    for (int o = 1; o < 64; o <<= 1) ls += __shfl_xor(ls, o);
    if (lane == 0) { mblk_g[b * NBX + bx] = m_blk; lblk_g[b * NBX + bx] = ls; }
  }

  // park U_att (f16) in overlay
#pragma unroll
  for (int n = 0; n < 8; ++n)
#pragma unroll
    for (int reg = 0; reg < 4; ++reg)
      Uatt[pr * 16 + g * 4 + reg][h * 128 + n * 16 + l15] =
          (_Float16)(Oacc[n][reg] * inv_l[reg]);
  __syncthreads();   // Uatt + wrow ready

  // ---- G writes (NT stores; cached loads) + weighted-Hm accumulation ----
  const int* pmb = mp + b * TP + i0;
  f32x4 acc = {0.f, 0.f, 0.f, 0.f};
#pragma unroll
  for (int it = 0; it < 8; ++it) {
    int idx4 = it * 1024 + tid;
    int r = idx4 >> 6, c = (idx4 & 63) * 4;
    float pm = (float)pmb[r];
    f32x4 hv = *(const f32x4*)&H[((size_t)b * TP + i0 + r) * D2_ + c];
    hv *= pm;                                   // Hm
    f16x4 u4 = *(const f16x4*)&Uatt[r][c];
    f32x4 u; u.x = (float)u4[0]; u.y = (float)u4[1]; u.z = (float)u4[2]; u.w = (float)u4[3];
    size_t ro = ((size_t)b * TP + i0 + r) * (4 * D2_);
    __builtin_nontemporal_store(hv, (f32x4*)&G[ro + c]);
    f32x4 up = u * pm;
    __builtin_nontemporal_store(up, (f32x4*)&G[ro + D2_ + c]);
    f32x4 hu; hu.x = hv.x * u.x; hu.y = hv.y * u.y; hu.z = hv.z * u.z; hu.w = hv.w * u.w;
    __builtin_nontemporal_store(hu, (f32x4*)&G[ro + 2 * D2_ + c]);
    acc += wrow[r] * hv;                        // h_att partial
  }

  __syncthreads();                // done reading Uatt
  Part[wv][lane] = acc;           // overlay
  __syncthreads();
  if (tid < 64) {
    f32x4 s = Part[0][tid];
#pragma unroll
    for (int k = 1; k < 16; ++k) s += Part[k][tid];
    *(f32x4*)&phat_ptr(G, b, bx)[tid * 4] = s;
  }
}

// ---------------- kernel 2: combine h_att partials ----------------
__global__ __launch_bounds__(256) void k_comb(const float* __restrict__ Gc,
    const float* __restrict__ mblk_g, const float* __restrict__ lblk_g,
    float* __restrict__ hatt) {
  int b = blockIdx.x, tid = threadIdx.x;
  __shared__ float sm[NBX], sl[NBX];
  if (tid < NBX) { sm[tid] = mblk_g[b * NBX + tid]; sl[tid] = lblk_g[b * NBX + tid]; }
  __syncthreads();
  float M = -1e30f;
#pragma unroll
  for (int k = 0; k < NBX; ++k) M = fmaxf(M, sm[k]);
  float L = 0.f;
#pragma unroll
  for (int k = 0; k < NBX; ++k) L += __expf(sm[k] - M) * sl[k];
  float acc = 0.f;
  for (int k = 0; k < NBX; ++k)
    acc += __expf(sm[k] - M) * Gc[(size_t)(9000 + b * NBX + k) * 1024 + 768 + tid];
  hatt[b * D2_ + tid] = acc / L;
}

// ---------------- kernel 3: G slice 3 = Hm * h_att (cached loads, NT store) ----------------
__global__ __launch_bounds__(256) void k_g3(const float* __restrict__ H,
    const int* __restrict__ mp, const float* __restrict__ hatt,
    float* __restrict__ G) {
  const int total = B_ * TP * (D2_ / 4);
  for (int idx = blockIdx.x * 256 + threadIdx.x; idx < total; idx += gridDim.x * 256) {
    int c4 = idx & 63;
    int i = (idx >> 6) & (TP - 1);
    int b = idx >> 18;
    float pm = (float)mp[b * TP + i];
    f32x4 h = *(const f32x4*)&H[((size_t)b * TP + i) * D2_ + c4 * 4];
    f32x4 ha = *(const f32x4*)&hatt[b * D2_ + c4 * 4];
    f32x4 o;
    o.x = h.x * pm * ha.x; o.y = h.y * pm * ha.y;
    o.z = h.z * pm * ha.z; o.w = h.w * pm * ha.w;
    __builtin_nontemporal_store(o, (f32x4*)&G[((size_t)b * TP + i) * (4 * D2_) + 3 * D2_ + c4 * 4]);
  }
}

extern "C" void kernel_launch(void* const* d_in, const int* in_sizes, int n_in,
                              void* d_out, int out_size, void* d_ws, size_t ws_size,
                              hipStream_t stream) {
  const float* H  = (const float*)d_in[0];
  const float* U  = (const float*)d_in[1];
  const float* w  = (const float*)d_in[2];
  const int*   mp = (const int*)d_in[3];
  const int*   mq = (const int*)d_in[4];
  float* G = (float*)d_out;

  float* ws   = (float*)d_ws;
  float* mblk = ws;             // 512
  float* lblk = mblk + 1024;    // 512
  float* hatt = lblk + 1024;    // 4096

  k_prep<<<dim3(NJT, B_), 256, 0, stream>>>(U, w, mq, G);
  k_main<<<dim3(NBX * B_), 1024, 0, stream>>>(H, w, mp, mblk, lblk, G);
  k_comb<<<dim3(B_), 256, 0, stream>>>(G, mblk, lblk, hatt);
  k_g3<<<dim3(2048), 256, 0, stream>>>(H, mp, hatt, G);
}